// Round 2
// baseline (8680.389 us; speedup 1.0000x reference)
//
#include <hip/hip_runtime.h>
#include <math.h>

#define NN 5000
#define TT 100
#define IND 32
#define FEATD 64
#define HIDD 64
#define OUTD 8
#define NHEADS 4
#define EE 160000
#define FIN 72
#define NHC 256   // HEADS*HID

__device__ __forceinline__ float fsig(float x){ return 1.f/(1.f+__expf(-x)); }
__device__ __forceinline__ float ftanh(float x){ return 1.f - 2.f/(__expf(2.f*x)+1.f); }
__device__ __forceinline__ float fsoftplus(float x){ return (x>20.f)? x : log1pf(__expf(x)); }

// ---------------- CSR build ----------------
__global__ __launch_bounds__(256) void count_edges(const int* __restrict__ dst,
                                                   int* __restrict__ cnt){
    int e = blockIdx.x*256 + threadIdx.x;
    if (e < EE) atomicAdd(&cnt[dst[e]], 1);
}

#define SCAN_N 5120
__global__ __launch_bounds__(1024) void scan_csr(const int* __restrict__ cnt,
                                                 int* __restrict__ row_ptr,
                                                 int* __restrict__ cursor){
    __shared__ int sa[SCAN_N];
    __shared__ int sb[SCAN_N];
    int tid = threadIdx.x;
    for (int i=tid;i<SCAN_N;i+=1024) sa[i] = (i<NN)?cnt[i]:0;
    __syncthreads();
    int *s=sa, *d=sb;
    for (int off=1; off<SCAN_N; off<<=1){
        for (int i=tid;i<SCAN_N;i+=1024){
            int v = s[i];
            if (i>=off) v += s[i-off];
            d[i] = v;
        }
        __syncthreads();
        int* t=s; s=d; d=t;
    }
    // s = inclusive scan
    for (int i=tid;i<=NN;i+=1024){
        int excl = (i==0)?0:s[i-1];
        row_ptr[i] = excl;
        if (i<NN) cursor[i] = excl;
    }
}

__global__ __launch_bounds__(256) void fill_edges(const int* __restrict__ src,
                                                  const int* __restrict__ dst,
                                                  int* __restrict__ cursor,
                                                  int* __restrict__ col){
    int e = blockIdx.x*256 + threadIdx.x;
    if (e < EE){
        int dn = dst[e];
        int pos = atomicAdd(&cursor[dn], 1);
        col[pos] = src[e];
    }
}

// ---------------- LSTM step ----------------
// block 256 = 4 waves; wave handles 4 nodes, lane = output dim d (0..63).
// Each thread computes gates (i,f,g,o) at dim d for 4 nodes.
__global__ __launch_bounds__(256) void lstm_step(const float* __restrict__ x,
                                                 const float* __restrict__ W_ih,
                                                 const float* __restrict__ W_hh,
                                                 const float* __restrict__ b_ih,
                                                 const float* __restrict__ b_hh,
                                                 float* __restrict__ h,
                                                 float* __restrict__ c,
                                                 int t){
    __shared__ float xh[16][96];   // per node: 32 x_t then 64 h
    int n0 = blockIdx.x * 16;
    int tid = threadIdx.x;
    for (int i=tid;i<16*96;i+=256){
        int node = i/96, kk = i%96;
        int n = n0 + node;
        float val = 0.f;
        if (n < NN) val = (kk<32) ? x[(n*TT + t)*IND + kk] : h[n*64 + (kk-32)];
        xh[node][kk] = val;
    }
    __syncthreads();
    int wave = tid >> 6;
    int lane = tid & 63;
    int nbase = wave*4;
    float acc[4][4];
    #pragma unroll
    for (int a=0;a<4;a++){
        #pragma unroll
        for (int g=0; g<4; g++) acc[a][g]=0.f;
    }
    for (int kk=0; kk<32; kk++){
        const float* Wr = W_ih + kk*256;
        float w0=Wr[lane], w1=Wr[lane+64], w2=Wr[lane+128], w3=Wr[lane+192];
        #pragma unroll
        for (int a=0;a<4;a++){
            float xv = xh[nbase+a][kk];
            acc[a][0] = fmaf(xv,w0,acc[a][0]);
            acc[a][1] = fmaf(xv,w1,acc[a][1]);
            acc[a][2] = fmaf(xv,w2,acc[a][2]);
            acc[a][3] = fmaf(xv,w3,acc[a][3]);
        }
    }
    for (int kk=0; kk<64; kk++){
        const float* Wr = W_hh + kk*256;
        float w0=Wr[lane], w1=Wr[lane+64], w2=Wr[lane+128], w3=Wr[lane+192];
        #pragma unroll
        for (int a=0;a<4;a++){
            float xv = xh[nbase+a][32+kk];
            acc[a][0] = fmaf(xv,w0,acc[a][0]);
            acc[a][1] = fmaf(xv,w1,acc[a][1]);
            acc[a][2] = fmaf(xv,w2,acc[a][2]);
            acc[a][3] = fmaf(xv,w3,acc[a][3]);
        }
    }
    float bi0 = b_ih[lane]     + b_hh[lane];
    float bi1 = b_ih[lane+64]  + b_hh[lane+64];
    float bi2 = b_ih[lane+128] + b_hh[lane+128];
    float bi3 = b_ih[lane+192] + b_hh[lane+192];
    #pragma unroll
    for (int a=0;a<4;a++){
        int n = n0 + nbase + a;
        if (n < NN){
            float gi = fsig(acc[a][0] + bi0);
            float gf = fsig(acc[a][1] + bi1);
            float gg = ftanh(acc[a][2] + bi2);
            float go = fsig(acc[a][3] + bi3);
            float cold = c[n*64 + lane];
            float cnew = gf*cold + gi*gg;
            float hnew = go*ftanh(cnew);
            c[n*64 + lane] = cnew;
            h[n*64 + lane] = hnew;
        }
    }
}

// ---------------- QKV + skip GEMM ----------------
// h_in = [h (64) | theta (8)]  (N,72) ; out cols: q(256) k(256) v(256) skip(64)
// block 256 threads, BN=8 nodes; thread computes 4 consecutive cols for all 8 nodes.
#define BN 8
__global__ __launch_bounds__(256) void qkv_step(const float* __restrict__ h,
                                                const float* __restrict__ theta,
                                                const float* __restrict__ Wq, const float* __restrict__ bq,
                                                const float* __restrict__ Wk, const float* __restrict__ bk,
                                                const float* __restrict__ Wv, const float* __restrict__ bv,
                                                const float* __restrict__ Wsk, const float* __restrict__ bsk,
                                                float* __restrict__ q, float* __restrict__ k,
                                                float* __restrict__ v, float* __restrict__ sk){
    __shared__ float hin[BN][FIN];
    int n0 = blockIdx.x * BN;
    int tid = threadIdx.x;
    for (int i=tid;i<BN*FIN;i+=256){
        int node=i/FIN, kk=i%FIN;
        int n = n0 + node;
        hin[node][kk] = (kk<64) ? h[n*64+kk] : theta[n*8 + (kk-64)];
    }
    __syncthreads();
    if (tid >= 208) return;
    int c4 = tid*4;
    const float* W; const float* b; float* out; int ncol; int cc;
    if (c4 < 256)      { W=Wq;  b=bq;  out=q;  ncol=256; cc=c4; }
    else if (c4 < 512) { W=Wk;  b=bk;  out=k;  ncol=256; cc=c4-256; }
    else if (c4 < 768) { W=Wv;  b=bv;  out=v;  ncol=256; cc=c4-512; }
    else               { W=Wsk; b=bsk; out=sk; ncol=64;  cc=c4-768; }
    float acc[BN][4];
    #pragma unroll
    for (int nn=0;nn<BN;nn++){
        #pragma unroll
        for (int j=0;j<4;j++) acc[nn][j]=0.f;
    }
    for (int kk=0; kk<FIN; kk++){
        float4 w = *reinterpret_cast<const float4*>(W + kk*ncol + cc);
        #pragma unroll
        for (int nn=0;nn<BN;nn++){
            float xv = hin[nn][kk];
            acc[nn][0] = fmaf(xv,w.x,acc[nn][0]);
            acc[nn][1] = fmaf(xv,w.y,acc[nn][1]);
            acc[nn][2] = fmaf(xv,w.z,acc[nn][2]);
            acc[nn][3] = fmaf(xv,w.w,acc[nn][3]);
        }
    }
    float4 bb = *reinterpret_cast<const float4*>(b + cc);
    #pragma unroll
    for (int nn=0;nn<BN;nn++){
        float4 o;
        o.x = acc[nn][0]+bb.x; o.y = acc[nn][1]+bb.y;
        o.z = acc[nn][2]+bb.z; o.w = acc[nn][3]+bb.w;
        *reinterpret_cast<float4*>(out + (n0+nn)*ncol + cc) = o;
    }
}

// ---------------- Edge attention + epilogue ----------------
// block 256 = 4 waves; wave = one dst node. lane: head = lane>>4, dims 4*(lane&15).
__global__ __launch_bounds__(256) void attn_step(const float* __restrict__ q,
                                                 const float* __restrict__ k,
                                                 const float* __restrict__ v,
                                                 const float* __restrict__ sk,
                                                 const int* __restrict__ row_ptr,
                                                 const int* __restrict__ col,
                                                 const float* __restrict__ Wmlp,
                                                 float* __restrict__ theta,
                                                 float* __restrict__ out,
                                                 int t){
    int wave = threadIdx.x >> 6;
    int lane = threadIdx.x & 63;
    int n = blockIdx.x*4 + wave;
    if (n >= NN) return;
    int e0 = row_ptr[n], e1 = row_ptr[n+1];
    float4 qv = *reinterpret_cast<const float4*>(q + n*NHC + lane*4);
    float m = -INFINITY, denom = 0.f;
    float ax=0.f, ay=0.f, az=0.f, aw=0.f;
    for (int e=e0; e<e1; e++){
        int s = col[e];
        float4 kv = *reinterpret_cast<const float4*>(k + s*NHC + lane*4);
        float p = qv.x*kv.x + qv.y*kv.y + qv.z*kv.z + qv.w*kv.w;
        p += __shfl_xor(p,1); p += __shfl_xor(p,2);
        p += __shfl_xor(p,4); p += __shfl_xor(p,8);
        float alpha = p * 0.125f;          // / sqrt(64)
        float mn = fmaxf(m, alpha);
        float scale = __expf(m - mn);      // 0 on first edge (m=-inf)
        float ee = __expf(alpha - mn);
        denom = denom*scale + ee;
        float4 vv = *reinterpret_cast<const float4*>(v + s*NHC + lane*4);
        ax = ax*scale + ee*vv.x;
        ay = ay*scale + ee*vv.y;
        az = az*scale + ee*vv.z;
        aw = aw*scale + ee*vv.w;
        m = mn;
    }
    float inv = 1.f / fmaxf(denom, 1e-16f);
    ax *= inv; ay *= inv; az *= inv; aw *= inv;
    // mean over 4 heads: lanes l, l^16, l^32, l^48
    ax += __shfl_xor(ax,16); ax += __shfl_xor(ax,32);
    ay += __shfl_xor(ay,16); ay += __shfl_xor(ay,32);
    az += __shfl_xor(az,16); az += __shfl_xor(az,32);
    aw += __shfl_xor(aw,16); aw += __shfl_xor(aw,32);
    int d0 = (lane & 15) * 4;
    float4 skv = *reinterpret_cast<const float4*>(sk + n*64 + d0);
    float t0 = ftanh(0.25f*ax + skv.x);
    float t1 = ftanh(0.25f*ay + skv.y);
    float t2 = ftanh(0.25f*az + skv.z);
    float t3 = ftanh(0.25f*aw + skv.w);
    // theta_new = tanh(hid) @ Wmlp  (64x8). Each lane: partial over its 4 dims.
    float p8[8];
    #pragma unroll
    for (int j=0;j<8;j++) p8[j]=0.f;
    #pragma unroll
    for (int j=0;j<8;j++){
        p8[j] = fmaf(t0, Wmlp[(d0+0)*8+j],
                fmaf(t1, Wmlp[(d0+1)*8+j],
                fmaf(t2, Wmlp[(d0+2)*8+j],
                fmaf(t3, Wmlp[(d0+3)*8+j], p8[j]))));
    }
    #pragma unroll
    for (int j=0;j<8;j++){
        p8[j] += __shfl_xor(p8[j],1);
        p8[j] += __shfl_xor(p8[j],2);
        p8[j] += __shfl_xor(p8[j],4);
        p8[j] += __shfl_xor(p8[j],8);
    }
    if (lane == 0){
        #pragma unroll
        for (int j=0;j<8;j++) theta[n*8+j] = p8[j];
        float ab0 = fsig(p8[5]);
        float ab1 = fsig(p8[6]);
        float a  = ab0*ab1;
        float bb = ab0 - a;
        float cc = fsoftplus(p8[7]);
        float* op = out + (n*TT + t)*8;
        op[0]=p8[0]; op[1]=p8[1]; op[2]=p8[2]; op[3]=p8[3]; op[4]=p8[4];
        op[5]=a; op[6]=bb; op[7]=cc;
    }
}

extern "C" void kernel_launch(void* const* d_in, const int* in_sizes, int n_in,
                              void* d_out, int out_size, void* d_ws, size_t ws_size,
                              hipStream_t stream) {
    const float* x     = (const float*)d_in[0];
    const int*   ei    = (const int*)  d_in[1];
    const float* W_ih  = (const float*)d_in[2];
    const float* W_hh  = (const float*)d_in[3];
    const float* b_ih  = (const float*)d_in[4];
    const float* b_hh  = (const float*)d_in[5];
    const float* Wq    = (const float*)d_in[6];
    const float* bq    = (const float*)d_in[7];
    const float* Wk    = (const float*)d_in[8];
    const float* bk    = (const float*)d_in[9];
    const float* Wv    = (const float*)d_in[10];
    const float* bv    = (const float*)d_in[11];
    const float* Wsk   = (const float*)d_in[12];
    const float* bsk   = (const float*)d_in[13];
    const float* Wmlp  = (const float*)d_in[14];
    float* out = (float*)d_out;

    // workspace layout
    float* f = (float*)d_ws;
    float* h     = f;               // N*64
    float* c     = h + NN*64;       // N*64
    float* theta = c + NN*64;       // N*8
    float* q     = theta + NN*8;    // N*256
    float* kk    = q + NN*NHC;      // N*256
    float* vv    = kk + NN*NHC;     // N*256
    float* skb   = vv + NN*NHC;     // N*64
    int* ip      = (int*)(skb + NN*64);
    int* row_ptr = ip;              // N+1
    int* cnt     = row_ptr + (NN+1);// N
    int* cursor  = cnt + NN;        // N
    int* colv    = cursor + NN;     // E

    const int* src = ei;
    const int* dst = ei + EE;

    // init state (h, c, theta contiguous) and counts
    hipMemsetAsync(h, 0, (size_t)NN*(64+64+8)*sizeof(float), stream);
    hipMemsetAsync(cnt, 0, (size_t)NN*sizeof(int), stream);

    count_edges<<<(EE+255)/256, 256, 0, stream>>>(dst, cnt);
    scan_csr<<<1, 1024, 0, stream>>>(cnt, row_ptr, cursor);
    fill_edges<<<(EE+255)/256, 256, 0, stream>>>(src, dst, cursor, colv);

    for (int t=0; t<TT; t++){
        lstm_step<<<(NN+15)/16, 256, 0, stream>>>(x, W_ih, W_hh, b_ih, b_hh, h, c, t);
        qkv_step<<<(NN+BN-1)/BN, 256, 0, stream>>>(h, theta, Wq,bq, Wk,bk, Wv,bv, Wsk,bsk,
                                                   q, kk, vv, skb);
        attn_step<<<(NN+3)/4, 256, 0, stream>>>(q, kk, vv, skb, row_ptr, colv, Wmlp,
                                                theta, out, t);
    }
}

// Round 3
// 6602.667 us; speedup vs baseline: 1.3147x; 1.3147x over previous
//
#include <hip/hip_runtime.h>
#include <math.h>

#define NN 5000
#define TT 100
#define IND 32
#define FEATD 64
#define HIDD 64
#define OUTD 8
#define NHEADS 4
#define EE 160000
#define FIN 72
#define NHC 256   // HEADS*HID

typedef unsigned short ushortx8 __attribute__((ext_vector_type(8)));
typedef unsigned short ushortx4 __attribute__((ext_vector_type(4)));

__device__ __forceinline__ float fsig(float x){ return 1.f/(1.f+__expf(-x)); }
__device__ __forceinline__ float ftanh(float x){ return 1.f - 2.f/(__expf(2.f*x)+1.f); }
__device__ __forceinline__ float fsoftplus(float x){ return (x>20.f)? x : log1pf(__expf(x)); }
__device__ __forceinline__ unsigned short f2bf(float f){
    unsigned int u = __float_as_uint(f);
    unsigned int r = (u + 0x7fffu + ((u>>16)&1u)) >> 16;
    return (unsigned short)r;
}
__device__ __forceinline__ float bf2f(unsigned short u){
    return __uint_as_float(((unsigned int)u)<<16);
}

// ---------------- CSR build ----------------
__global__ __launch_bounds__(256) void count_edges(const int* __restrict__ dst,
                                                   int* __restrict__ cnt){
    int e = blockIdx.x*256 + threadIdx.x;
    if (e < EE) atomicAdd(&cnt[dst[e]], 1);
}

#define SCAN_N 5120
__global__ __launch_bounds__(1024) void scan_csr(const int* __restrict__ cnt,
                                                 int* __restrict__ row_ptr,
                                                 int* __restrict__ cursor){
    __shared__ int sa[SCAN_N];
    __shared__ int sb[SCAN_N];
    int tid = threadIdx.x;
    for (int i=tid;i<SCAN_N;i+=1024) sa[i] = (i<NN)?cnt[i]:0;
    __syncthreads();
    int *s=sa, *d=sb;
    for (int off=1; off<SCAN_N; off<<=1){
        for (int i=tid;i<SCAN_N;i+=1024){
            int v = s[i];
            if (i>=off) v += s[i-off];
            d[i] = v;
        }
        __syncthreads();
        int* t=s; s=d; d=t;
    }
    for (int i=tid;i<=NN;i+=1024){
        int excl = (i==0)?0:s[i-1];
        row_ptr[i] = excl;
        if (i<NN) cursor[i] = excl;
    }
}

__global__ __launch_bounds__(256) void fill_edges(const int* __restrict__ src,
                                                  const int* __restrict__ dst,
                                                  int* __restrict__ cursor,
                                                  int* __restrict__ col){
    int e = blockIdx.x*256 + threadIdx.x;
    if (e < EE){
        int dn = dst[e];
        int pos = atomicAdd(&cursor[dn], 1);
        col[pos] = src[e];
    }
}

// ---------------- fused LSTM + QKV step ----------------
// 8 nodes / block, 256 threads.
// Phase A (LSTM): thread = (dim d = tid&63, node-pair na/na+4), 4 gates each.
// Phase B (QKV): thread tid<208 computes 4 consecutive cols of [q|k|v|skip]
//   for all 8 nodes. k,v are written bf16 INTERLEAVED: kv[n][l*8+0..3]=k dims
//   4l..4l+3, [l*8+4..7]=v dims 4l..4l+3 -> attn lane l does ONE 16B load/edge.
__global__ __launch_bounds__(256) void lstm_qkv_step(
    const float* __restrict__ x,
    const float* __restrict__ W_ih, const float* __restrict__ W_hh,
    const float* __restrict__ b_ih, const float* __restrict__ b_hh,
    const float* __restrict__ Wq, const float* __restrict__ bq,
    const float* __restrict__ Wk, const float* __restrict__ bk,
    const float* __restrict__ Wv, const float* __restrict__ bv,
    const float* __restrict__ Wsk, const float* __restrict__ bsk,
    float* __restrict__ h, float* __restrict__ c,
    const float* __restrict__ theta,
    float* __restrict__ q, float* __restrict__ sk,
    unsigned short* __restrict__ kv, int t)
{
    __shared__ float xh[8][96];    // per node: 32 x_t | 64 h_prev
    __shared__ float hin[8][72];   // per node: 64 h_new | 8 theta
    int n0 = blockIdx.x * 8;
    int tid = threadIdx.x;
    for (int i=tid; i<8*96; i+=256){
        int node = i/96, kk = i%96;
        int n = n0 + node;
        xh[node][kk] = (kk<32) ? x[(n*TT + t)*IND + kk] : h[n*64 + (kk-32)];
    }
    if (tid < 64){
        int node = tid>>3, j = tid&7;
        hin[node][64+j] = theta[(n0+node)*8 + j];
    }
    __syncthreads();

    // ---- Phase A: LSTM ----
    int d  = tid & 63;
    int na = tid >> 6;     // wave id 0..3 -> nodes na and na+4
    float acc[2][4];
    #pragma unroll
    for (int p=0;p<2;p++){
        #pragma unroll
        for (int g=0;g<4;g++) acc[p][g]=0.f;
    }
    for (int kk=0; kk<32; kk++){
        const float* Wr = W_ih + kk*256;
        float w0=Wr[d], w1=Wr[d+64], w2=Wr[d+128], w3=Wr[d+192];
        float x0 = xh[na][kk], x1 = xh[na+4][kk];
        acc[0][0]=fmaf(x0,w0,acc[0][0]); acc[0][1]=fmaf(x0,w1,acc[0][1]);
        acc[0][2]=fmaf(x0,w2,acc[0][2]); acc[0][3]=fmaf(x0,w3,acc[0][3]);
        acc[1][0]=fmaf(x1,w0,acc[1][0]); acc[1][1]=fmaf(x1,w1,acc[1][1]);
        acc[1][2]=fmaf(x1,w2,acc[1][2]); acc[1][3]=fmaf(x1,w3,acc[1][3]);
    }
    for (int kk=0; kk<64; kk++){
        const float* Wr = W_hh + kk*256;
        float w0=Wr[d], w1=Wr[d+64], w2=Wr[d+128], w3=Wr[d+192];
        float x0 = xh[na][32+kk], x1 = xh[na+4][32+kk];
        acc[0][0]=fmaf(x0,w0,acc[0][0]); acc[0][1]=fmaf(x0,w1,acc[0][1]);
        acc[0][2]=fmaf(x0,w2,acc[0][2]); acc[0][3]=fmaf(x0,w3,acc[0][3]);
        acc[1][0]=fmaf(x1,w0,acc[1][0]); acc[1][1]=fmaf(x1,w1,acc[1][1]);
        acc[1][2]=fmaf(x1,w2,acc[1][2]); acc[1][3]=fmaf(x1,w3,acc[1][3]);
    }
    float bi0 = b_ih[d]     + b_hh[d];
    float bi1 = b_ih[d+64]  + b_hh[d+64];
    float bi2 = b_ih[d+128] + b_hh[d+128];
    float bi3 = b_ih[d+192] + b_hh[d+192];
    #pragma unroll
    for (int p=0;p<2;p++){
        int node = na + p*4;
        int n = n0 + node;
        float gi = fsig(acc[p][0] + bi0);
        float gf = fsig(acc[p][1] + bi1);
        float gg = ftanh(acc[p][2] + bi2);
        float go = fsig(acc[p][3] + bi3);
        float cold = c[n*64 + d];
        float cnew = gf*cold + gi*gg;
        float hnew = go*ftanh(cnew);
        c[n*64 + d] = cnew;
        h[n*64 + d] = hnew;
        hin[node][d] = hnew;
    }
    __syncthreads();

    // ---- Phase B: QKV + skip ----
    if (tid < 208){
        int c4 = tid*4;
        const float* W; const float* b; int ncol; int cc; int kind;
        if (c4 < 256)      { W=Wq;  b=bq;  ncol=256; cc=c4;     kind=0; }
        else if (c4 < 512) { W=Wk;  b=bk;  ncol=256; cc=c4-256; kind=1; }
        else if (c4 < 768) { W=Wv;  b=bv;  ncol=256; cc=c4-512; kind=2; }
        else               { W=Wsk; b=bsk; ncol=64;  cc=c4-768; kind=3; }
        float acc2[8][4];
        #pragma unroll
        for (int nn=0;nn<8;nn++){
            #pragma unroll
            for (int j=0;j<4;j++) acc2[nn][j]=0.f;
        }
        for (int kk=0; kk<FIN; kk++){
            float4 w = *reinterpret_cast<const float4*>(W + kk*ncol + cc);
            #pragma unroll
            for (int nn=0;nn<8;nn++){
                float xv = hin[nn][kk];
                acc2[nn][0]=fmaf(xv,w.x,acc2[nn][0]);
                acc2[nn][1]=fmaf(xv,w.y,acc2[nn][1]);
                acc2[nn][2]=fmaf(xv,w.z,acc2[nn][2]);
                acc2[nn][3]=fmaf(xv,w.w,acc2[nn][3]);
            }
        }
        float4 bb = *reinterpret_cast<const float4*>(b + cc);
        #pragma unroll
        for (int nn=0;nn<8;nn++){
            int n = n0 + nn;
            float o0=acc2[nn][0]+bb.x, o1=acc2[nn][1]+bb.y;
            float o2=acc2[nn][2]+bb.z, o3=acc2[nn][3]+bb.w;
            if (kind == 0){
                float4 o = {o0,o1,o2,o3};
                *reinterpret_cast<float4*>(q + n*NHC + cc) = o;
            } else if (kind == 3){
                float4 o = {o0,o1,o2,o3};
                *reinterpret_cast<float4*>(sk + n*64 + cc) = o;
            } else {
                ushortx4 u;
                u[0]=f2bf(o0); u[1]=f2bf(o1); u[2]=f2bf(o2); u[3]=f2bf(o3);
                // k cols cc -> kv offset cc*2 ; v cols cc -> cc*2+4
                int off = n*512 + cc*2 + ((kind==2)?4:0);
                *reinterpret_cast<ushortx4*>(kv + off) = u;
            }
        }
    }
}

// ---------------- Edge attention + epilogue ----------------
// block 256 = 4 waves; wave = one dst node. lane: head = lane>>4, dims 4*(lane&15).
// One 16B bf16 load per lane per edge ([k4|v4] interleaved), next edge prefetched.
__global__ __launch_bounds__(256) void attn_step(const float* __restrict__ q,
                                                 const unsigned short* __restrict__ kv,
                                                 const float* __restrict__ sk,
                                                 const int* __restrict__ row_ptr,
                                                 const int* __restrict__ col,
                                                 const float* __restrict__ Wmlp,
                                                 float* __restrict__ theta,
                                                 float* __restrict__ out,
                                                 int t){
    int wave = threadIdx.x >> 6;
    int lane = threadIdx.x & 63;
    int n = blockIdx.x*4 + wave;
    if (n >= NN) return;
    int e0 = row_ptr[n], e1 = row_ptr[n+1];
    float4 qv = *reinterpret_cast<const float4*>(q + n*NHC + lane*4);
    float m = -INFINITY, denom = 0.f;
    float ax=0.f, ay=0.f, az=0.f, aw=0.f;
    if (e0 < e1){
        int s = col[e0];
        ushortx8 cur = *reinterpret_cast<const ushortx8*>(kv + (size_t)s*512 + lane*8);
        for (int e=e0; e<e1; e++){
            ushortx8 u = cur;
            if (e+1 < e1){
                int s2 = col[e+1];
                cur = *reinterpret_cast<const ushortx8*>(kv + (size_t)s2*512 + lane*8);
            }
            float p = qv.x*bf2f(u[0]) + qv.y*bf2f(u[1])
                    + qv.z*bf2f(u[2]) + qv.w*bf2f(u[3]);
            p += __shfl_xor(p,1); p += __shfl_xor(p,2);
            p += __shfl_xor(p,4); p += __shfl_xor(p,8);
            float alpha = p * 0.125f;          // / sqrt(64)
            float mn = fmaxf(m, alpha);
            float scale = __expf(m - mn);      // 0 on first edge (m=-inf)
            float ee = __expf(alpha - mn);
            denom = denom*scale + ee;
            ax = ax*scale + ee*bf2f(u[4]);
            ay = ay*scale + ee*bf2f(u[5]);
            az = az*scale + ee*bf2f(u[6]);
            aw = aw*scale + ee*bf2f(u[7]);
            m = mn;
        }
    }
    float inv = 1.f / fmaxf(denom, 1e-16f);
    ax *= inv; ay *= inv; az *= inv; aw *= inv;
    // mean over 4 heads: lanes l, l^16, l^32, l^48
    ax += __shfl_xor(ax,16); ax += __shfl_xor(ax,32);
    ay += __shfl_xor(ay,16); ay += __shfl_xor(ay,32);
    az += __shfl_xor(az,16); az += __shfl_xor(az,32);
    aw += __shfl_xor(aw,16); aw += __shfl_xor(aw,32);
    int d0 = (lane & 15) * 4;
    float4 skv = *reinterpret_cast<const float4*>(sk + n*64 + d0);
    float t0 = ftanh(0.25f*ax + skv.x);
    float t1 = ftanh(0.25f*ay + skv.y);
    float t2 = ftanh(0.25f*az + skv.z);
    float t3 = ftanh(0.25f*aw + skv.w);
    float p8[8];
    #pragma unroll
    for (int j=0;j<8;j++){
        p8[j] = fmaf(t0, Wmlp[(d0+0)*8+j],
                fmaf(t1, Wmlp[(d0+1)*8+j],
                fmaf(t2, Wmlp[(d0+2)*8+j],
                     t3* Wmlp[(d0+3)*8+j])));
    }
    #pragma unroll
    for (int j=0;j<8;j++){
        p8[j] += __shfl_xor(p8[j],1);
        p8[j] += __shfl_xor(p8[j],2);
        p8[j] += __shfl_xor(p8[j],4);
        p8[j] += __shfl_xor(p8[j],8);
    }
    if (lane == 0){
        float4 t0v = {p8[0],p8[1],p8[2],p8[3]};
        float4 t1v = {p8[4],p8[5],p8[6],p8[7]};
        *reinterpret_cast<float4*>(theta + n*8)     = t0v;
        *reinterpret_cast<float4*>(theta + n*8 + 4) = t1v;
        float ab0 = fsig(p8[5]);
        float ab1 = fsig(p8[6]);
        float a  = ab0*ab1;
        float bb = ab0 - a;
        float cc = fsoftplus(p8[7]);
        float4 o0 = {p8[0],p8[1],p8[2],p8[3]};
        float4 o1 = {p8[4],a,bb,cc};
        float* op = out + ((size_t)n*TT + t)*8;
        *reinterpret_cast<float4*>(op)     = o0;
        *reinterpret_cast<float4*>(op + 4) = o1;
    }
}

extern "C" void kernel_launch(void* const* d_in, const int* in_sizes, int n_in,
                              void* d_out, int out_size, void* d_ws, size_t ws_size,
                              hipStream_t stream) {
    const float* x     = (const float*)d_in[0];
    const int*   ei    = (const int*)  d_in[1];
    const float* W_ih  = (const float*)d_in[2];
    const float* W_hh  = (const float*)d_in[3];
    const float* b_ih  = (const float*)d_in[4];
    const float* b_hh  = (const float*)d_in[5];
    const float* Wq    = (const float*)d_in[6];
    const float* bq    = (const float*)d_in[7];
    const float* Wk    = (const float*)d_in[8];
    const float* bk    = (const float*)d_in[9];
    const float* Wv    = (const float*)d_in[10];
    const float* bv    = (const float*)d_in[11];
    const float* Wsk   = (const float*)d_in[12];
    const float* bsk   = (const float*)d_in[13];
    const float* Wmlp  = (const float*)d_in[14];
    float* out = (float*)d_out;

    // workspace layout (16B-aligned sections)
    float* f = (float*)d_ws;
    float* h     = f;                    // N*64
    float* c     = h + NN*64;            // N*64
    float* theta = c + NN*64;            // N*8
    float* q     = theta + NN*8;         // N*256
    float* skb   = q + NN*NHC;           // N*64
    unsigned short* kvb = (unsigned short*)(skb + NN*64);  // N*512 bf16
    int* ip      = (int*)(kvb + (size_t)NN*512);
    int* row_ptr = ip;                   // N+1
    int* cnt     = row_ptr + (NN+1);     // N
    int* cursor  = cnt + NN;             // N
    int* colv    = cursor + NN;          // E

    const int* src = ei;
    const int* dst = ei + EE;

    // init state (h, c, theta contiguous) and counts
    hipMemsetAsync(h, 0, (size_t)NN*(64+64+8)*sizeof(float), stream);
    hipMemsetAsync(cnt, 0, (size_t)NN*sizeof(int), stream);

    count_edges<<<(EE+255)/256, 256, 0, stream>>>(dst, cnt);
    scan_csr<<<1, 1024, 0, stream>>>(cnt, row_ptr, cursor);
    fill_edges<<<(EE+255)/256, 256, 0, stream>>>(src, dst, cursor, colv);

    for (int t=0; t<TT; t++){
        lstm_qkv_step<<<NN/8, 256, 0, stream>>>(x, W_ih, W_hh, b_ih, b_hh,
                                                Wq,bq, Wk,bk, Wv,bv, Wsk,bsk,
                                                h, c, theta, q, skb, kvb, t);
        attn_step<<<(NN+3)/4, 256, 0, stream>>>(q, kvb, skb, row_ptr, colv, Wmlp,
                                                theta, out, t);
    }
}

// Round 4
// 6321.349 us; speedup vs baseline: 1.3732x; 1.0445x over previous
//
#include <hip/hip_runtime.h>
#include <math.h>

#define NN 5000
#define TT 100
#define IND 32
#define FEATD 64
#define HIDD 64
#define OUTD 8
#define NHEADS 4
#define EE 160000
#define FIN 72
#define NHC 256   // HEADS*HID

typedef unsigned short ushortx8 __attribute__((ext_vector_type(8)));
typedef unsigned short ushortx4 __attribute__((ext_vector_type(4)));

__device__ __forceinline__ float fsig(float x){ return 1.f/(1.f+__expf(-x)); }
__device__ __forceinline__ float ftanh(float x){ return 1.f - 2.f/(__expf(2.f*x)+1.f); }
__device__ __forceinline__ float fsoftplus(float x){ return (x>20.f)? x : log1pf(__expf(x)); }
__device__ __forceinline__ unsigned short f2bf(float f){
    unsigned int u = __float_as_uint(f);
    unsigned int r = (u + 0x7fffu + ((u>>16)&1u)) >> 16;
    return (unsigned short)r;
}
__device__ __forceinline__ float bf2f(unsigned short u){
    return __uint_as_float(((unsigned int)u)<<16);
}

// ---------------- CSR build ----------------
__global__ __launch_bounds__(256) void count_edges(const int* __restrict__ dst,
                                                   int* __restrict__ cnt){
    int e = blockIdx.x*256 + threadIdx.x;
    if (e < EE) atomicAdd(&cnt[dst[e]], 1);
}

#define SCAN_N 5120
__global__ __launch_bounds__(1024) void scan_csr(const int* __restrict__ cnt,
                                                 int* __restrict__ row_ptr,
                                                 int* __restrict__ cursor){
    __shared__ int sa[SCAN_N];
    __shared__ int sb[SCAN_N];
    int tid = threadIdx.x;
    for (int i=tid;i<SCAN_N;i+=1024) sa[i] = (i<NN)?cnt[i]:0;
    __syncthreads();
    int *s=sa, *d=sb;
    for (int off=1; off<SCAN_N; off<<=1){
        for (int i=tid;i<SCAN_N;i+=1024){
            int v = s[i];
            if (i>=off) v += s[i-off];
            d[i] = v;
        }
        __syncthreads();
        int* t=s; s=d; d=t;
    }
    for (int i=tid;i<=NN;i+=1024){
        int excl = (i==0)?0:s[i-1];
        row_ptr[i] = excl;
        if (i<NN) cursor[i] = excl;
    }
}

__global__ __launch_bounds__(256) void fill_edges(const int* __restrict__ src,
                                                  const int* __restrict__ dst,
                                                  int* __restrict__ cursor,
                                                  int* __restrict__ col){
    int e = blockIdx.x*256 + threadIdx.x;
    if (e < EE){
        int dn = dst[e];
        int pos = atomicAdd(&cursor[dn], 1);
        col[pos] = src[e];
    }
}

// ---------------- fused LSTM + QKV step ----------------
// 4 nodes / block (1250 blocks), 256 threads.
// Phase A (LSTM): wave = one node, lane = dim d, computes 4 gates.
// Phase B (QKV): thread tid<208 computes 4 consecutive cols of [q|k|v|skip]
//   for all 4 nodes. k,v written bf16 INTERLEAVED: kv[n][l*8+0..3]=k dims
//   4l..4l+3, [l*8+4..7]=v dims 4l..4l+3 -> attn lane l does ONE 16B load/edge.
__global__ __launch_bounds__(256) void lstm_qkv_step(
    const float* __restrict__ x,
    const float* __restrict__ W_ih, const float* __restrict__ W_hh,
    const float* __restrict__ b_ih, const float* __restrict__ b_hh,
    const float* __restrict__ Wq, const float* __restrict__ bq,
    const float* __restrict__ Wk, const float* __restrict__ bk,
    const float* __restrict__ Wv, const float* __restrict__ bv,
    const float* __restrict__ Wsk, const float* __restrict__ bsk,
    float* __restrict__ h, float* __restrict__ c,
    const float* __restrict__ theta,
    float* __restrict__ q, float* __restrict__ sk,
    unsigned short* __restrict__ kv, int t)
{
    __shared__ float xh[4][96];    // per node: 32 x_t | 64 h_prev
    __shared__ float hin[4][72];   // per node: 64 h_new | 8 theta
    int n0 = blockIdx.x * 4;
    int tid = threadIdx.x;
    for (int i=tid; i<4*96; i+=256){
        int node = i/96, kk = i%96;
        int n = n0 + node;
        xh[node][kk] = (kk<32) ? x[(n*TT + t)*IND + kk] : h[n*64 + (kk-32)];
    }
    if (tid < 32){
        int node = tid>>3, j = tid&7;
        hin[node][64+j] = theta[(n0+node)*8 + j];
    }
    __syncthreads();

    // ---- Phase A: LSTM (wave = node) ----
    int d  = tid & 63;
    int wv = tid >> 6;
    float a0=0.f, a1=0.f, a2=0.f, a3=0.f;
    #pragma unroll 4
    for (int kk=0; kk<32; kk++){
        const float* Wr = W_ih + kk*256;
        float xv = xh[wv][kk];
        a0 = fmaf(xv, Wr[d],     a0);
        a1 = fmaf(xv, Wr[d+64],  a1);
        a2 = fmaf(xv, Wr[d+128], a2);
        a3 = fmaf(xv, Wr[d+192], a3);
    }
    #pragma unroll 4
    for (int kk=0; kk<64; kk++){
        const float* Wr = W_hh + kk*256;
        float xv = xh[wv][32+kk];
        a0 = fmaf(xv, Wr[d],     a0);
        a1 = fmaf(xv, Wr[d+64],  a1);
        a2 = fmaf(xv, Wr[d+128], a2);
        a3 = fmaf(xv, Wr[d+192], a3);
    }
    {
        int n = n0 + wv;
        float gi = fsig (a0 + b_ih[d]     + b_hh[d]);
        float gf = fsig (a1 + b_ih[d+64]  + b_hh[d+64]);
        float gg = ftanh(a2 + b_ih[d+128] + b_hh[d+128]);
        float go = fsig (a3 + b_ih[d+192] + b_hh[d+192]);
        float cold = c[n*64 + d];
        float cnew = gf*cold + gi*gg;
        float hnew = go*ftanh(cnew);
        c[n*64 + d] = cnew;
        h[n*64 + d] = hnew;
        hin[wv][d] = hnew;
    }
    __syncthreads();

    // ---- Phase B: QKV + skip ----
    if (tid < 208){
        int c4 = tid*4;
        const float* W; const float* b; int ncol; int cc; int kind;
        if (c4 < 256)      { W=Wq;  b=bq;  ncol=256; cc=c4;     kind=0; }
        else if (c4 < 512) { W=Wk;  b=bk;  ncol=256; cc=c4-256; kind=1; }
        else if (c4 < 768) { W=Wv;  b=bv;  ncol=256; cc=c4-512; kind=2; }
        else               { W=Wsk; b=bsk; ncol=64;  cc=c4-768; kind=3; }
        float acc2[4][4];
        #pragma unroll
        for (int nn=0;nn<4;nn++){
            #pragma unroll
            for (int j=0;j<4;j++) acc2[nn][j]=0.f;
        }
        for (int kk=0; kk<FIN; kk++){
            float4 w = *reinterpret_cast<const float4*>(W + kk*ncol + cc);
            #pragma unroll
            for (int nn=0;nn<4;nn++){
                float xv = hin[nn][kk];
                acc2[nn][0]=fmaf(xv,w.x,acc2[nn][0]);
                acc2[nn][1]=fmaf(xv,w.y,acc2[nn][1]);
                acc2[nn][2]=fmaf(xv,w.z,acc2[nn][2]);
                acc2[nn][3]=fmaf(xv,w.w,acc2[nn][3]);
            }
        }
        float4 bb = *reinterpret_cast<const float4*>(b + cc);
        #pragma unroll
        for (int nn=0;nn<4;nn++){
            int n = n0 + nn;
            float o0=acc2[nn][0]+bb.x, o1=acc2[nn][1]+bb.y;
            float o2=acc2[nn][2]+bb.z, o3=acc2[nn][3]+bb.w;
            if (kind == 0){
                float4 o = {o0,o1,o2,o3};
                *reinterpret_cast<float4*>(q + n*NHC + cc) = o;
            } else if (kind == 3){
                float4 o = {o0,o1,o2,o3};
                *reinterpret_cast<float4*>(sk + n*64 + cc) = o;
            } else {
                ushortx4 u;
                u[0]=f2bf(o0); u[1]=f2bf(o1); u[2]=f2bf(o2); u[3]=f2bf(o3);
                int off = n*512 + cc*2 + ((kind==2)?4:0);
                *reinterpret_cast<ushortx4*>(kv + off) = u;
            }
        }
    }
}

// ---------------- Edge attention + epilogue ----------------
// block 256 = 4 waves = 2 nodes x 2 waves. Each wave does online softmax over
// every other edge of its node (2-deep prefetch); states merged via LDS.
// lane: head = lane>>4, dims 4*(lane&15). One 16B bf16 load/lane/edge.
__global__ __launch_bounds__(256) void attn_step(const float* __restrict__ q,
                                                 const unsigned short* __restrict__ kv,
                                                 const float* __restrict__ sk,
                                                 const int* __restrict__ row_ptr,
                                                 const int* __restrict__ col,
                                                 const float* __restrict__ Wmlp,
                                                 float* __restrict__ theta,
                                                 float* __restrict__ out,
                                                 int t){
    __shared__ float mrg[2][6][64];
    int wvid = threadIdx.x >> 6;
    int lane = threadIdx.x & 63;
    int ln   = wvid >> 1;          // local node 0/1
    int half = wvid & 1;           // which wave of the pair
    int n = blockIdx.x*2 + ln;     // NN even, grid*2 == NN
    int e0 = row_ptr[n], e1 = row_ptr[n+1];
    float4 qv = *reinterpret_cast<const float4*>(q + n*NHC + lane*4);
    qv.x *= 0.125f; qv.y *= 0.125f; qv.z *= 0.125f; qv.w *= 0.125f;
    float m = -INFINITY, denom = 0.f;
    float ax=0.f, ay=0.f, az=0.f, aw=0.f;
    {
        int e = e0 + half;
        ushortx8 b0, b1;
        if (e < e1)   b0 = *reinterpret_cast<const ushortx8*>(kv + (size_t)col[e]*512   + lane*8);
        if (e+2 < e1) b1 = *reinterpret_cast<const ushortx8*>(kv + (size_t)col[e+2]*512 + lane*8);
        for (; e < e1; e += 2){
            ushortx8 u = b0; b0 = b1;
            if (e+4 < e1)
                b1 = *reinterpret_cast<const ushortx8*>(kv + (size_t)col[e+4]*512 + lane*8);
            float p = qv.x*bf2f(u[0]) + qv.y*bf2f(u[1])
                    + qv.z*bf2f(u[2]) + qv.w*bf2f(u[3]);
            p += __shfl_xor(p,1); p += __shfl_xor(p,2);
            p += __shfl_xor(p,4); p += __shfl_xor(p,8);
            float mn = fmaxf(m, p);
            float scale = __expf(m - mn);      // 0 on first edge (m=-inf)
            float ee = __expf(p - mn);
            denom = denom*scale + ee;
            ax = ax*scale + ee*bf2f(u[4]);
            ay = ay*scale + ee*bf2f(u[5]);
            az = az*scale + ee*bf2f(u[6]);
            aw = aw*scale + ee*bf2f(u[7]);
            m = mn;
        }
    }
    if (half == 1){
        mrg[ln][0][lane]=m;  mrg[ln][1][lane]=denom;
        mrg[ln][2][lane]=ax; mrg[ln][3][lane]=ay;
        mrg[ln][4][lane]=az; mrg[ln][5][lane]=aw;
    }
    __syncthreads();
    if (half == 1) return;

    // merge partner wave's online-softmax state
    {
        float m1 = mrg[ln][0][lane];
        float mM = fmaxf(m, m1);
        float s0 = (m  == -INFINITY) ? 0.f : __expf(m  - mM);
        float s1 = (m1 == -INFINITY) ? 0.f : __expf(m1 - mM);
        denom = denom*s0 + mrg[ln][1][lane]*s1;
        ax = ax*s0 + mrg[ln][2][lane]*s1;
        ay = ay*s0 + mrg[ln][3][lane]*s1;
        az = az*s0 + mrg[ln][4][lane]*s1;
        aw = aw*s0 + mrg[ln][5][lane]*s1;
    }
    float inv = 1.f / fmaxf(denom, 1e-16f);
    ax *= inv; ay *= inv; az *= inv; aw *= inv;
    // mean over 4 heads: lanes l, l^16, l^32, l^48
    ax += __shfl_xor(ax,16); ax += __shfl_xor(ax,32);
    ay += __shfl_xor(ay,16); ay += __shfl_xor(ay,32);
    az += __shfl_xor(az,16); az += __shfl_xor(az,32);
    aw += __shfl_xor(aw,16); aw += __shfl_xor(aw,32);
    int d0 = (lane & 15) * 4;
    float4 skv = *reinterpret_cast<const float4*>(sk + n*64 + d0);
    float t0 = ftanh(0.25f*ax + skv.x);
    float t1 = ftanh(0.25f*ay + skv.y);
    float t2 = ftanh(0.25f*az + skv.z);
    float t3 = ftanh(0.25f*aw + skv.w);
    float p8[8];
    #pragma unroll
    for (int j=0;j<8;j++){
        p8[j] = fmaf(t0, Wmlp[(d0+0)*8+j],
                fmaf(t1, Wmlp[(d0+1)*8+j],
                fmaf(t2, Wmlp[(d0+2)*8+j],
                     t3* Wmlp[(d0+3)*8+j])));
    }
    #pragma unroll
    for (int j=0;j<8;j++){
        p8[j] += __shfl_xor(p8[j],1);
        p8[j] += __shfl_xor(p8[j],2);
        p8[j] += __shfl_xor(p8[j],4);
        p8[j] += __shfl_xor(p8[j],8);
    }
    if (lane == 0){
        float4 t0v = {p8[0],p8[1],p8[2],p8[3]};
        float4 t1v = {p8[4],p8[5],p8[6],p8[7]};
        *reinterpret_cast<float4*>(theta + n*8)     = t0v;
        *reinterpret_cast<float4*>(theta + n*8 + 4) = t1v;
        float ab0 = fsig(p8[5]);
        float ab1 = fsig(p8[6]);
        float a  = ab0*ab1;
        float bb = ab0 - a;
        float cc = fsoftplus(p8[7]);
        float4 o0 = {p8[0],p8[1],p8[2],p8[3]};
        float4 o1 = {p8[4],a,bb,cc};
        float* op = out + ((size_t)n*TT + t)*8;
        *reinterpret_cast<float4*>(op)     = o0;
        *reinterpret_cast<float4*>(op + 4) = o1;
    }
}

extern "C" void kernel_launch(void* const* d_in, const int* in_sizes, int n_in,
                              void* d_out, int out_size, void* d_ws, size_t ws_size,
                              hipStream_t stream) {
    const float* x     = (const float*)d_in[0];
    const int*   ei    = (const int*)  d_in[1];
    const float* W_ih  = (const float*)d_in[2];
    const float* W_hh  = (const float*)d_in[3];
    const float* b_ih  = (const float*)d_in[4];
    const float* b_hh  = (const float*)d_in[5];
    const float* Wq    = (const float*)d_in[6];
    const float* bq    = (const float*)d_in[7];
    const float* Wk    = (const float*)d_in[8];
    const float* bk    = (const float*)d_in[9];
    const float* Wv    = (const float*)d_in[10];
    const float* bv    = (const float*)d_in[11];
    const float* Wsk   = (const float*)d_in[12];
    const float* bsk   = (const float*)d_in[13];
    const float* Wmlp  = (const float*)d_in[14];
    float* out = (float*)d_out;

    // workspace layout (16B-aligned sections)
    float* f = (float*)d_ws;
    float* h     = f;                    // N*64
    float* c     = h + NN*64;            // N*64
    float* theta = c + NN*64;            // N*8
    float* q     = theta + NN*8;         // N*256
    float* skb   = q + NN*NHC;           // N*64
    unsigned short* kvb = (unsigned short*)(skb + NN*64);  // N*512 bf16
    int* ip      = (int*)(kvb + (size_t)NN*512);
    int* row_ptr = ip;                   // N+1
    int* cnt     = row_ptr + (NN+1);     // N
    int* cursor  = cnt + NN;             // N
    int* colv    = cursor + NN;          // E

    const int* src = ei;
    const int* dst = ei + EE;

    hipMemsetAsync(h, 0, (size_t)NN*(64+64+8)*sizeof(float), stream);
    hipMemsetAsync(cnt, 0, (size_t)NN*sizeof(int), stream);

    count_edges<<<(EE+255)/256, 256, 0, stream>>>(dst, cnt);
    scan_csr<<<1, 1024, 0, stream>>>(cnt, row_ptr, cursor);
    fill_edges<<<(EE+255)/256, 256, 0, stream>>>(src, dst, cursor, colv);

    for (int t=0; t<TT; t++){
        lstm_qkv_step<<<NN/4, 256, 0, stream>>>(x, W_ih, W_hh, b_ih, b_hh,
                                                Wq,bq, Wk,bk, Wv,bv, Wsk,bsk,
                                                h, c, theta, q, skb, kvb, t);
        attn_step<<<NN/2, 256, 0, stream>>>(q, kvb, skb, row_ptr, colv, Wmlp,
                                            theta, out, t);
    }
}

// Round 5
// 5548.355 us; speedup vs baseline: 1.5645x; 1.1393x over previous
//
#include <hip/hip_runtime.h>
#include <math.h>

#define NN 5000
#define TT 100
#define IND 32
#define FEATD 64
#define HIDD 64
#define OUTD 8
#define NHEADS 4
#define EE 160000
#define FIN 72
#define NHC 256   // HEADS*HID

typedef unsigned short ushortx8 __attribute__((ext_vector_type(8)));
typedef unsigned short ushortx4 __attribute__((ext_vector_type(4)));

__device__ __forceinline__ float fsig(float x){ return 1.f/(1.f+__expf(-x)); }
__device__ __forceinline__ float ftanh(float x){ return 1.f - 2.f/(__expf(2.f*x)+1.f); }
__device__ __forceinline__ float fsoftplus(float x){ return (x>20.f)? x : log1pf(__expf(x)); }
__device__ __forceinline__ unsigned short f2bf(float f){
    unsigned int u = __float_as_uint(f);
    unsigned int r = (u + 0x7fffu + ((u>>16)&1u)) >> 16;
    return (unsigned short)r;
}
__device__ __forceinline__ float bf2f(unsigned short u){
    return __uint_as_float(((unsigned int)u)<<16);
}

// ---------------- CSR build ----------------
__global__ __launch_bounds__(256) void count_edges(const int* __restrict__ dst,
                                                   int* __restrict__ cnt){
    int e = blockIdx.x*256 + threadIdx.x;
    if (e < EE) atomicAdd(&cnt[dst[e]], 1);
}

#define SCAN_N 5120
__global__ __launch_bounds__(1024) void scan_csr(const int* __restrict__ cnt,
                                                 int* __restrict__ row_ptr,
                                                 int* __restrict__ cursor){
    __shared__ int sa[SCAN_N];
    __shared__ int sb[SCAN_N];
    int tid = threadIdx.x;
    for (int i=tid;i<SCAN_N;i+=1024) sa[i] = (i<NN)?cnt[i]:0;
    __syncthreads();
    int *s=sa, *d=sb;
    for (int off=1; off<SCAN_N; off<<=1){
        for (int i=tid;i<SCAN_N;i+=1024){
            int v = s[i];
            if (i>=off) v += s[i-off];
            d[i] = v;
        }
        __syncthreads();
        int* t=s; s=d; d=t;
    }
    for (int i=tid;i<=NN;i+=1024){
        int excl = (i==0)?0:s[i-1];
        row_ptr[i] = excl;
        if (i<NN) cursor[i] = excl;
    }
}

__global__ __launch_bounds__(256) void fill_edges(const int* __restrict__ src,
                                                  const int* __restrict__ dst,
                                                  int* __restrict__ cursor,
                                                  int* __restrict__ col){
    int e = blockIdx.x*256 + threadIdx.x;
    if (e < EE){
        int dn = dst[e];
        int pos = atomicAdd(&cursor[dn], 1);
        col[pos] = src[e];
    }
}

// ---------------- fused LSTM + QKV step ----------------
// 8 nodes / block (625 blocks), 256 threads.
// Phase A (LSTM): wave = nodes (wv, wv+4), lane = dim d, 4 gates each.
// Phase B (QKV): thread tid<208 computes 4 consecutive cols of [q|k|v|skip]
//   for all 8 nodes (weight slice read once, reused 8x). k,v written bf16
//   INTERLEAVED: kv[n][l*8+0..3]=k dims 4l.., [l*8+4..7]=v dims 4l..
__global__ __launch_bounds__(256) void lstm_qkv_step(
    const float* __restrict__ x,
    const float* __restrict__ W_ih, const float* __restrict__ W_hh,
    const float* __restrict__ b_ih, const float* __restrict__ b_hh,
    const float* __restrict__ Wq, const float* __restrict__ bq,
    const float* __restrict__ Wk, const float* __restrict__ bk,
    const float* __restrict__ Wv, const float* __restrict__ bv,
    const float* __restrict__ Wsk, const float* __restrict__ bsk,
    float* __restrict__ h, float* __restrict__ c,
    const float* __restrict__ theta,
    float* __restrict__ q, float* __restrict__ sk,
    unsigned short* __restrict__ kv, int t)
{
    __shared__ float xh[8][96];    // per node: 32 x_t | 64 h_prev
    __shared__ float hin[8][72];   // per node: 64 h_new | 8 theta
    int n0 = blockIdx.x * 8;
    int tid = threadIdx.x;
    for (int i=tid; i<8*96; i+=256){
        int node = i/96, kk = i%96;
        int n = n0 + node;
        xh[node][kk] = (kk<32) ? x[(n*TT + t)*IND + kk] : h[n*64 + (kk-32)];
    }
    if (tid < 64){
        int node = tid>>3, j = tid&7;
        hin[node][64+j] = theta[(n0+node)*8 + j];
    }
    __syncthreads();

    // ---- Phase A: LSTM (wave = node pair wv, wv+4) ----
    int d  = tid & 63;
    int wv = tid >> 6;
    float acc[2][4];
    #pragma unroll
    for (int p=0;p<2;p++){
        #pragma unroll
        for (int g=0;g<4;g++) acc[p][g]=0.f;
    }
    #pragma unroll 8
    for (int kk=0; kk<32; kk++){
        const float* Wr = W_ih + kk*256;
        float w0=Wr[d], w1=Wr[d+64], w2=Wr[d+128], w3=Wr[d+192];
        float x0 = xh[wv][kk], x1 = xh[wv+4][kk];
        acc[0][0]=fmaf(x0,w0,acc[0][0]); acc[0][1]=fmaf(x0,w1,acc[0][1]);
        acc[0][2]=fmaf(x0,w2,acc[0][2]); acc[0][3]=fmaf(x0,w3,acc[0][3]);
        acc[1][0]=fmaf(x1,w0,acc[1][0]); acc[1][1]=fmaf(x1,w1,acc[1][1]);
        acc[1][2]=fmaf(x1,w2,acc[1][2]); acc[1][3]=fmaf(x1,w3,acc[1][3]);
    }
    #pragma unroll 8
    for (int kk=0; kk<64; kk++){
        const float* Wr = W_hh + kk*256;
        float w0=Wr[d], w1=Wr[d+64], w2=Wr[d+128], w3=Wr[d+192];
        float x0 = xh[wv][32+kk], x1 = xh[wv+4][32+kk];
        acc[0][0]=fmaf(x0,w0,acc[0][0]); acc[0][1]=fmaf(x0,w1,acc[0][1]);
        acc[0][2]=fmaf(x0,w2,acc[0][2]); acc[0][3]=fmaf(x0,w3,acc[0][3]);
        acc[1][0]=fmaf(x1,w0,acc[1][0]); acc[1][1]=fmaf(x1,w1,acc[1][1]);
        acc[1][2]=fmaf(x1,w2,acc[1][2]); acc[1][3]=fmaf(x1,w3,acc[1][3]);
    }
    float bi0 = b_ih[d]     + b_hh[d];
    float bi1 = b_ih[d+64]  + b_hh[d+64];
    float bi2 = b_ih[d+128] + b_hh[d+128];
    float bi3 = b_ih[d+192] + b_hh[d+192];
    #pragma unroll
    for (int p=0;p<2;p++){
        int node = wv + p*4;
        int n = n0 + node;
        float gi = fsig (acc[p][0] + bi0);
        float gf = fsig (acc[p][1] + bi1);
        float gg = ftanh(acc[p][2] + bi2);
        float go = fsig (acc[p][3] + bi3);
        float cold = c[n*64 + d];
        float cnew = gf*cold + gi*gg;
        float hnew = go*ftanh(cnew);
        c[n*64 + d] = cnew;
        h[n*64 + d] = hnew;
        hin[node][d] = hnew;
    }
    __syncthreads();

    // ---- Phase B: QKV + skip ----
    if (tid < 208){
        int c4 = tid*4;
        const float* W; const float* b; int ncol; int cc; int kind;
        if (c4 < 256)      { W=Wq;  b=bq;  ncol=256; cc=c4;     kind=0; }
        else if (c4 < 512) { W=Wk;  b=bk;  ncol=256; cc=c4-256; kind=1; }
        else if (c4 < 768) { W=Wv;  b=bv;  ncol=256; cc=c4-512; kind=2; }
        else               { W=Wsk; b=bsk; ncol=64;  cc=c4-768; kind=3; }
        float acc2[8][4];
        #pragma unroll
        for (int nn=0;nn<8;nn++){
            #pragma unroll
            for (int j=0;j<4;j++) acc2[nn][j]=0.f;
        }
        #pragma unroll 4
        for (int kk=0; kk<FIN; kk++){
            float4 w = *reinterpret_cast<const float4*>(W + kk*ncol + cc);
            #pragma unroll
            for (int nn=0;nn<8;nn++){
                float xv = hin[nn][kk];
                acc2[nn][0]=fmaf(xv,w.x,acc2[nn][0]);
                acc2[nn][1]=fmaf(xv,w.y,acc2[nn][1]);
                acc2[nn][2]=fmaf(xv,w.z,acc2[nn][2]);
                acc2[nn][3]=fmaf(xv,w.w,acc2[nn][3]);
            }
        }
        float4 bb = *reinterpret_cast<const float4*>(b + cc);
        #pragma unroll
        for (int nn=0;nn<8;nn++){
            int n = n0 + nn;
            float o0=acc2[nn][0]+bb.x, o1=acc2[nn][1]+bb.y;
            float o2=acc2[nn][2]+bb.z, o3=acc2[nn][3]+bb.w;
            if (kind == 0){
                float4 o = {o0,o1,o2,o3};
                *reinterpret_cast<float4*>(q + n*NHC + cc) = o;
            } else if (kind == 3){
                float4 o = {o0,o1,o2,o3};
                *reinterpret_cast<float4*>(sk + n*64 + cc) = o;
            } else {
                ushortx4 u;
                u[0]=f2bf(o0); u[1]=f2bf(o1); u[2]=f2bf(o2); u[3]=f2bf(o3);
                int off = n*512 + cc*2 + ((kind==2)?4:0);
                *reinterpret_cast<ushortx4*>(kv + off) = u;
            }
        }
    }
}

// ---------------- Edge attention + epilogue ----------------
// block 256 = 4 waves = 2 nodes x 2 waves. Each wave runs TWO independent
// online-softmax chains (even/odd of its edge subset, 2-deep prefetch each
// -> 4 outstanding gathers + 2x ILP on the dependent shuffle/exp chain).
// lane: head = lane>>4, dims 4*(lane&15). One 16B bf16 load/lane/edge.
#define LOADKV(e) (*reinterpret_cast<const ushortx8*>(kv + (size_t)col[(e)]*512 + lane*8))
__global__ __launch_bounds__(256) void attn_step(const float* __restrict__ q,
                                                 const unsigned short* __restrict__ kv,
                                                 const float* __restrict__ sk,
                                                 const int* __restrict__ row_ptr,
                                                 const int* __restrict__ col,
                                                 const float* __restrict__ Wmlp,
                                                 float* __restrict__ theta,
                                                 float* __restrict__ out,
                                                 int t){
    __shared__ float mrg[2][6][64];
    int wvid = threadIdx.x >> 6;
    int lane = threadIdx.x & 63;
    int ln   = wvid >> 1;          // local node 0/1
    int half = wvid & 1;           // which wave of the pair
    int n = blockIdx.x*2 + ln;     // NN even, grid*2 == NN
    int e0 = row_ptr[n], e1 = row_ptr[n+1];
    float4 qv = *reinterpret_cast<const float4*>(q + n*NHC + lane*4);
    qv.x *= 0.125f; qv.y *= 0.125f; qv.z *= 0.125f; qv.w *= 0.125f;

    float mA=-INFINITY, dA=0.f, axA=0.f, ayA=0.f, azA=0.f, awA=0.f;
    float mB=-INFINITY, dB=0.f, axB=0.f, ayB=0.f, azB=0.f, awB=0.f;
    int eA = e0 + half;            // chain A: stride 4
    int eB = eA + 2;               // chain B: stride 4
    ushortx8 bA0, bA1, bB0, bB1;
    if (eA   < e1) bA0 = LOADKV(eA);
    if (eB   < e1) bB0 = LOADKV(eB);
    if (eA+4 < e1) bA1 = LOADKV(eA+4);
    if (eB+4 < e1) bB1 = LOADKV(eB+4);
    while (eA < e1){
        ushortx8 uA = bA0; bA0 = bA1;
        if (eA+8 < e1) bA1 = LOADKV(eA+8);
        bool hasB = (eB < e1);
        ushortx8 uB = bB0; bB0 = bB1;
        if (eB+8 < e1) bB1 = LOADKV(eB+8);

        float pA = qv.x*bf2f(uA[0]) + qv.y*bf2f(uA[1])
                 + qv.z*bf2f(uA[2]) + qv.w*bf2f(uA[3]);
        float pB = qv.x*bf2f(uB[0]) + qv.y*bf2f(uB[1])
                 + qv.z*bf2f(uB[2]) + qv.w*bf2f(uB[3]);
        pA += __shfl_xor(pA,1); pB += __shfl_xor(pB,1);
        pA += __shfl_xor(pA,2); pB += __shfl_xor(pB,2);
        pA += __shfl_xor(pA,4); pB += __shfl_xor(pB,4);
        pA += __shfl_xor(pA,8); pB += __shfl_xor(pB,8);

        {   // chain A update
            float mn = fmaxf(mA, pA);
            float sc = __expf(mA - mn);
            float ee = __expf(pA - mn);
            dA = dA*sc + ee;
            axA = axA*sc + ee*bf2f(uA[4]);
            ayA = ayA*sc + ee*bf2f(uA[5]);
            azA = azA*sc + ee*bf2f(uA[6]);
            awA = awA*sc + ee*bf2f(uA[7]);
            mA = mn;
        }
        if (hasB){ // chain B update
            float mn = fmaxf(mB, pB);
            float sc = __expf(mB - mn);
            float ee = __expf(pB - mn);
            dB = dB*sc + ee;
            axB = axB*sc + ee*bf2f(uB[4]);
            ayB = ayB*sc + ee*bf2f(uB[5]);
            azB = azB*sc + ee*bf2f(uB[6]);
            awB = awB*sc + ee*bf2f(uB[7]);
            mB = mn;
        }
        eA += 4; eB += 4;
    }
    // merge chain B into A (in-register)
    float m, denom, ax, ay, az, aw;
    {
        float mM = fmaxf(mA, mB);
        float s0 = (mA == -INFINITY) ? 0.f : __expf(mA - mM);
        float s1 = (mB == -INFINITY) ? 0.f : __expf(mB - mM);
        denom = dA*s0 + dB*s1;
        ax = axA*s0 + axB*s1;
        ay = ayA*s0 + ayB*s1;
        az = azA*s0 + azB*s1;
        aw = awA*s0 + awB*s1;
        m = mM;
    }
    if (half == 1){
        mrg[ln][0][lane]=m;  mrg[ln][1][lane]=denom;
        mrg[ln][2][lane]=ax; mrg[ln][3][lane]=ay;
        mrg[ln][4][lane]=az; mrg[ln][5][lane]=aw;
    }
    __syncthreads();
    if (half == 1) return;

    // merge partner wave's state
    {
        float m1 = mrg[ln][0][lane];
        float mM = fmaxf(m, m1);
        float s0 = (m  == -INFINITY) ? 0.f : __expf(m  - mM);
        float s1 = (m1 == -INFINITY) ? 0.f : __expf(m1 - mM);
        denom = denom*s0 + mrg[ln][1][lane]*s1;
        ax = ax*s0 + mrg[ln][2][lane]*s1;
        ay = ay*s0 + mrg[ln][3][lane]*s1;
        az = az*s0 + mrg[ln][4][lane]*s1;
        aw = aw*s0 + mrg[ln][5][lane]*s1;
    }
    float inv = 1.f / fmaxf(denom, 1e-16f);
    ax *= inv; ay *= inv; az *= inv; aw *= inv;
    // mean over 4 heads
    ax += __shfl_xor(ax,16); ax += __shfl_xor(ax,32);
    ay += __shfl_xor(ay,16); ay += __shfl_xor(ay,32);
    az += __shfl_xor(az,16); az += __shfl_xor(az,32);
    aw += __shfl_xor(aw,16); aw += __shfl_xor(aw,32);
    int d0 = (lane & 15) * 4;
    float4 skv = *reinterpret_cast<const float4*>(sk + n*64 + d0);
    float t0 = ftanh(0.25f*ax + skv.x);
    float t1 = ftanh(0.25f*ay + skv.y);
    float t2 = ftanh(0.25f*az + skv.z);
    float t3 = ftanh(0.25f*aw + skv.w);
    float p8[8];
    #pragma unroll
    for (int j=0;j<8;j++){
        p8[j] = fmaf(t0, Wmlp[(d0+0)*8+j],
                fmaf(t1, Wmlp[(d0+1)*8+j],
                fmaf(t2, Wmlp[(d0+2)*8+j],
                     t3* Wmlp[(d0+3)*8+j])));
    }
    #pragma unroll
    for (int j=0;j<8;j++){
        p8[j] += __shfl_xor(p8[j],1);
        p8[j] += __shfl_xor(p8[j],2);
        p8[j] += __shfl_xor(p8[j],4);
        p8[j] += __shfl_xor(p8[j],8);
    }
    if (lane == 0){
        float4 t0v = {p8[0],p8[1],p8[2],p8[3]};
        float4 t1v = {p8[4],p8[5],p8[6],p8[7]};
        *reinterpret_cast<float4*>(theta + n*8)     = t0v;
        *reinterpret_cast<float4*>(theta + n*8 + 4) = t1v;
        float ab0 = fsig(p8[5]);
        float ab1 = fsig(p8[6]);
        float a  = ab0*ab1;
        float bb = ab0 - a;
        float cc = fsoftplus(p8[7]);
        float4 o0 = {p8[0],p8[1],p8[2],p8[3]};
        float4 o1 = {p8[4],a,bb,cc};
        float* op = out + ((size_t)n*TT + t)*8;
        *reinterpret_cast<float4*>(op)     = o0;
        *reinterpret_cast<float4*>(op + 4) = o1;
    }
}

extern "C" void kernel_launch(void* const* d_in, const int* in_sizes, int n_in,
                              void* d_out, int out_size, void* d_ws, size_t ws_size,
                              hipStream_t stream) {
    const float* x     = (const float*)d_in[0];
    const int*   ei    = (const int*)  d_in[1];
    const float* W_ih  = (const float*)d_in[2];
    const float* W_hh  = (const float*)d_in[3];
    const float* b_ih  = (const float*)d_in[4];
    const float* b_hh  = (const float*)d_in[5];
    const float* Wq    = (const float*)d_in[6];
    const float* bq    = (const float*)d_in[7];
    const float* Wk    = (const float*)d_in[8];
    const float* bk    = (const float*)d_in[9];
    const float* Wv    = (const float*)d_in[10];
    const float* bv    = (const float*)d_in[11];
    const float* Wsk   = (const float*)d_in[12];
    const float* bsk   = (const float*)d_in[13];
    const float* Wmlp  = (const float*)d_in[14];
    float* out = (float*)d_out;

    // workspace layout (16B-aligned sections)
    float* f = (float*)d_ws;
    float* h     = f;                    // N*64
    float* c     = h + NN*64;            // N*64
    float* theta = c + NN*64;            // N*8
    float* q     = theta + NN*8;         // N*256
    float* skb   = q + NN*NHC;           // N*64
    unsigned short* kvb = (unsigned short*)(skb + NN*64);  // N*512 bf16
    int* ip      = (int*)(kvb + (size_t)NN*512);
    int* row_ptr = ip;                   // N+1
    int* cnt     = row_ptr + (NN+1);     // N
    int* cursor  = cnt + NN;             // N
    int* colv    = cursor + NN;          // E

    const int* src = ei;
    const int* dst = ei + EE;

    hipMemsetAsync(h, 0, (size_t)NN*(64+64+8)*sizeof(float), stream);
    hipMemsetAsync(cnt, 0, (size_t)NN*sizeof(int), stream);

    count_edges<<<(EE+255)/256, 256, 0, stream>>>(dst, cnt);
    scan_csr<<<1, 1024, 0, stream>>>(cnt, row_ptr, cursor);
    fill_edges<<<(EE+255)/256, 256, 0, stream>>>(src, dst, cursor, colv);

    for (int t=0; t<TT; t++){
        lstm_qkv_step<<<NN/8, 256, 0, stream>>>(x, W_ih, W_hh, b_ih, b_hh,
                                                Wq,bq, Wk,bk, Wv,bv, Wsk,bsk,
                                                h, c, theta, q, skb, kvb, t);
        attn_step<<<NN/2, 256, 0, stream>>>(q, kvb, skb, row_ptr, colv, Wmlp,
                                            theta, out, t);
    }
}